// Round 1
// baseline (370.692 us; speedup 1.0000x reference)
//
#include <hip/hip_runtime.h>
#include <hip/hip_bf16.h>
#include <cmath>

// Problem constants
constexpr int Bc = 128, Tc = 128, Ac = 16;
constexpr int Dc = 256, Hc = 512, Qc = 128, QIc = 512, Vc = 64, NTk = 13;
// Masked logits: ref emits -inf; harness needs finite there.
constexpr float NEG_BIG = -1e30f;
// fp8 scaling: weights x16, activations x16 (exact pow2), acc x 1/256.
constexpr float ACT_SCALE = 16.f;
constexpr float ACC_SCALE = 1.f / 256.f;
constexpr float ACC_TO_ACT = 1.f / 16.f;  // ACC_SCALE*ACT_SCALE (epilogue fold)

typedef unsigned int uint;
typedef uint uint2v __attribute__((ext_vector_type(2)));
typedef int i32x8 __attribute__((ext_vector_type(8)));
typedef float f32x4 __attribute__((ext_vector_type(4)));

// MX-scaled fp8 MFMA, K=128, unit E8M0 scales (0x7F = 2^0). cbsz=0/blgp=0 = fp8 e4m3.
// All-constant scale/sel args -> robust to sel/scale arg-order details.
#define MFMA128(a, b, c) __builtin_amdgcn_mfma_scale_f32_16x16x128_f8f6f4( \
    (a), (b), (c), 0, 0, 0, 0x7F7F7F7F, 0, 0x7F7F7F7F)

__device__ __forceinline__ unsigned short f2bfu(float f) {
  __hip_bfloat16 h = __float2bfloat16(f);
  return *(unsigned short*)&h;
}
__device__ __forceinline__ float bf2f(short s) {
  return __uint_as_float(((unsigned)(unsigned short)s) << 16);
}
__device__ __forceinline__ uint pack4_fp8(float a, float b, float c, float d) {
  uint v = 0;
  v = __builtin_amdgcn_cvt_pk_fp8_f32(a, b, v, 0);
  v = __builtin_amdgcn_cvt_pk_fp8_f32(c, d, v, 1);
  return v;
}

// ---------------------------------------------------------------------------
// Weight transform: fp32 [P][K][N] -> fp8 (x16) K=128 MFMA A-fragments.
// frag[p][nt][kc][lane][32B]: n = nt*16 + (lane&15),
//   k = kc*128 + (lane>>4)*32 + byte (32 contiguous k-bytes per lane).
// A/B lane->k maps are symmetric on gfx950 16x16; B side (LDS activations)
// uses the identical byte<->k convention, so any shared bijection is
// self-consistent, and unit scales make scale-block mapping irrelevant.
// ---------------------------------------------------------------------------
__global__ void transform_all(const float* __restrict__ kW1, const float* __restrict__ kW2,
                              const float* __restrict__ kW3, const float* __restrict__ qW,
                              int* __restrict__ kW1f, int* __restrict__ kW2f,
                              int* __restrict__ kW3f, int* __restrict__ qWf) {
  int gid = blockIdx.x * 256 + threadIdx.x;  // 65536 total
  const float* W;
  int* dst;
  int NT, KC, N, local;
  if (gid < 16384) {            // kW1: P4 x NT32 x KC2
    W = kW1; dst = kW1f; NT = 32; KC = 2; N = 512; local = gid;
  } else if (gid < 49152) {     // kW2: P4 x NT32 x KC4
    W = kW2; dst = kW2f; NT = 32; KC = 4; N = 512; local = gid - 16384;
  } else if (gid < 57344) {     // kW3: P4 x NT8 x KC4
    W = kW3; dst = kW3f; NT = 8; KC = 4; N = 128; local = gid - 49152;
  } else {                      // qW:  P4 x NT8 x KC4
    W = qW; dst = qWf; NT = 8; KC = 4; N = 128; local = gid - 57344;
  }
  int lane = local & 63;
  int frag = local >> 6;
  int kc = frag % KC;
  int rest = frag / KC;
  int nt = rest % NT;
  int pp = rest / NT;
  int K = KC * 128;
  int n = nt * 16 + (lane & 15);
  int k0 = kc * 128 + (lane >> 4) * 32;
  const float* src = W + ((size_t)pp * K + k0) * N + n;
  i32x8 v;
#pragma unroll
  for (int jj = 0; jj < 8; ++jj) {
    float f0 = src[(size_t)(4 * jj + 0) * N] * ACT_SCALE;
    float f1 = src[(size_t)(4 * jj + 1) * N] * ACT_SCALE;
    float f2 = src[(size_t)(4 * jj + 2) * N] * ACT_SCALE;
    float f3 = src[(size_t)(4 * jj + 3) * N] * ACT_SCALE;
    v[jj] = (int)pack4_fp8(f0, f1, f2, f3);
  }
  *(i32x8*)(dst + (size_t)local * 8) = v;
}

// ---------------------------------------------------------------------------
// K=128 MX fp8 MFMA layer, operand-swapped (weights = A, activations = B).
// One wave: WT weight(outdim)-tiles x AT action-tiles, K = KC*128.
// B-frag: lane (c=lane&15, q=lane>>4) reads 32B at row c(+16*at), logical
// byte off q*32 + kc*128, with 1-bit bank half-swap: physical ^= (c&1)<<4.
// Row strides are ==32 mod 128B so rows spread over 4 bank-phases; with the
// half-swap each b128 wave-read is 8 dwords/bank = conflict-free minimum.
// C/D: lane holds action col = lane&15, 4 consecutive outdims (4q+r).
// Weight A-frag: scalar (readfirstlane'd) base + lane*32B -> saddr loads.
// OUTMODE: 0 = fp8 x16 (hidden, swizzled write), 1 = bf16 KV (linear),
//          2 = fp32 token rows (QY, linear).  CMASK: row clamp for beA(4 rows).
// ---------------------------------------------------------------------------
template <int KC, int WT, int AT, bool RELU, int OUTMODE, int SIN, int SOUT, int CMASK>
__device__ __forceinline__ void layer128(
    const char* __restrict__ aB, void* __restrict__ o0,
    const int* __restrict__ Wfi, const float* __restrict__ bias,
    int wt0, int lane) {
  const int c = lane & 15, q = lane >> 4;
  const int sw = (c & 1) << 4;
  const char* ap = aB + (c & CMASK) * SIN + q * 32;

  f32x4 acc[WT][AT];
#pragma unroll
  for (int wt = 0; wt < WT; ++wt)
#pragma unroll
    for (int at = 0; at < AT; ++at)
#pragma unroll
      for (int r = 0; r < 4; ++r) acc[wt][at][r] = 0.f;

#pragma unroll 1
  for (int kc = 0; kc < KC; ++kc) {
    i32x8 bfr[AT];
#pragma unroll
    for (int at = 0; at < AT; ++at) {
      const char* pa = ap + at * 16 * SIN + kc * 128;
      uint4 u0 = *(const uint4*)(pa + sw);
      uint4 u1 = *(const uint4*)(pa + (16 ^ sw));
      i32x8 bv;
      bv[0] = (int)u0.x; bv[1] = (int)u0.y; bv[2] = (int)u0.z; bv[3] = (int)u0.w;
      bv[4] = (int)u1.x; bv[5] = (int)u1.y; bv[6] = (int)u1.z; bv[7] = (int)u1.w;
      bfr[at] = bv;
    }
#pragma unroll
    for (int wt = 0; wt < WT; ++wt) {
      // wt0 is SGPR (readfirstlane) -> scalar base + lane*32B voffset
      const i32x8 wv = *(const i32x8*)(Wfi + ((size_t)((wt0 + wt) * KC + kc)) * 512 + lane * 8);
#pragma unroll
      for (int at = 0; at < AT; ++at)
        acc[wt][at] = MFMA128(wv, bfr[at], acc[wt][at]);
    }
  }

#pragma unroll
  for (int wt = 0; wt < WT; ++wt) {
    const int nb = (wt0 + wt) * 16 + 4 * q;  // outdim base for this lane
    float4 bv = *(const float4*)(bias + nb);
#pragma unroll
    for (int at = 0; at < AT; ++at) {
      const int row = at * 16 + c;  // action row
      if (OUTMODE == 0) {
        float s0 = fmaf(acc[wt][at][0], ACC_TO_ACT, bv.x * ACT_SCALE);
        float s1 = fmaf(acc[wt][at][1], ACC_TO_ACT, bv.y * ACT_SCALE);
        float s2 = fmaf(acc[wt][at][2], ACC_TO_ACT, bv.z * ACT_SCALE);
        float s3 = fmaf(acc[wt][at][3], ACC_TO_ACT, bv.w * ACT_SCALE);
        if (RELU) {
          s0 = fmaxf(s0, 0.f); s1 = fmaxf(s1, 0.f);
          s2 = fmaxf(s2, 0.f); s3 = fmaxf(s3, 0.f);
        }
        // swizzled write: bit4 of byte-offset ^= row parity (matches reader)
        *(uint*)((char*)o0 + row * SOUT + (nb ^ sw)) = pack4_fp8(s0, s1, s2, s3);
      } else if (OUTMODE == 1) {
        float s0 = fmaf(acc[wt][at][0], ACC_SCALE, bv.x);
        float s1 = fmaf(acc[wt][at][1], ACC_SCALE, bv.y);
        float s2 = fmaf(acc[wt][at][2], ACC_SCALE, bv.z);
        float s3 = fmaf(acc[wt][at][3], ACC_SCALE, bv.w);
        uint2v u;
        u.x = ((uint)f2bfu(s1) << 16) | f2bfu(s0);
        u.y = ((uint)f2bfu(s3) << 16) | f2bfu(s2);
        *(uint2v*)((short*)o0 + row * SOUT + nb) = u;
      } else {
        if (c < 4) {  // only real token rows
          float4 st;
          st.x = fmaf(acc[wt][at][0], ACC_SCALE, bv.x);
          st.y = fmaf(acc[wt][at][1], ACC_SCALE, bv.y);
          st.z = fmaf(acc[wt][at][2], ACC_SCALE, bv.z);
          st.w = fmaf(acc[wt][at][3], ACC_SCALE, bv.w);
          *(float4*)((float*)o0 + c * SOUT + nb) = st;
        }
      }
    }
  }
}

// ---------------------------------------------------------------------------
// Main fused kernel: 512 threads (8 waves), 64 rows (4 tokens x 16 actions).
// 8 waves halves redundant B-panel LDS reads vs 16; launch_bounds(512,4)
// caps VGPR at 128 -> 2 blocks/CU (LDS 74.5KB x2 = 149KB fits 160KB).
// phase = blockIdx&3 -> per-phase 512KB fp8 weight set stays L2-resident.
// ---------------------------------------------------------------------------
constexpr int SX = 288;   // Xs row stride bytes  (256 data + 32; ==32 mod 128)
constexpr int SH = 544;   // H1/H2/beA row stride (512 data + 32; ==32 mod 128)
constexpr int SKV = 136;  // KV stride (bf16 elems, linear)
constexpr int SQY = 132;  // QY stride (fp32 elems, linear)

__global__ __launch_bounds__(512, 4) void policy_main(
    const float* __restrict__ be, const int* __restrict__ va,
    const int* __restrict__ phase, const int* __restrict__ trick,
    const float* __restrict__ emb0, const float* __restrict__ emb1,
    const float* __restrict__ emb2, const float* __restrict__ ln_g,
    const float* __restrict__ ln_b,
    const float* __restrict__ kb1, const float* __restrict__ kb2,
    const float* __restrict__ kb3, const float* __restrict__ qb,
    const int* __restrict__ kW1f, const int* __restrict__ kW2f,
    const int* __restrict__ kW3f, const int* __restrict__ qWf,
    float* __restrict__ out) {
  __shared__ __align__(16) char bufA[64 * SH];   // Xs [64][SX] then H2 [64][SH]
  __shared__ __align__(16) char bufB[64 * SH];   // H1 [64][SH]; then KV [64][SKV] bf16
  __shared__ __align__(16) char beAb[4 * SH];    // be tokens fp8 (4 rows, swizzled)
  __shared__ __align__(16) float QYs[4 * SQY];
  __shared__ float attn_s[64];
  __shared__ int inval_s[64];
  __shared__ int ph_s[4], tr_s[4];

  char* Xs = bufA;
  char* H2 = bufA;
  char* H1 = bufB;
  short* KV = (short*)bufB;  // H1 dead after layer2

  const int tid = threadIdx.x;
  const int lane = tid & 63;
  const int wu = __builtin_amdgcn_readfirstlane(tid >> 6);  // wave id -> SGPR
  const int p = blockIdx.x & 3;
  const int g = blockIdx.x >> 2;
  const int b = g >> 3;
  const int t0 = p * 32 + (g & 7) * 4;
  const int bt0 = b * Tc + t0;

  // ---- stage 0 (no internal barrier): masks, phase/trick, beA, LN->Xs ----
  if (tid < 64) {
    inval_s[tid] = (va[((size_t)bt0 * Ac + tid) * 3] == -1);
  } else if (tid < 68) {
    ph_s[tid - 64] = phase[bt0 + tid - 64];
  } else if (tid < 72) {
    tr_s[tid - 68] = trick[bt0 + tid - 68];
  }
  if (tid < 128) {  // beA: 4 token rows x 512 dims fp8 (x16), swizzled 16B units
    const int tok = tid >> 5, li = tid & 31;
    const float4* bp4 = (const float4*)(be + ((size_t)(bt0 + tok)) * QIc + li * 16);
    float4 a0 = bp4[0], a1 = bp4[1], a2 = bp4[2], a3 = bp4[3];
    uint4 v;
    v.x = pack4_fp8(a0.x * ACT_SCALE, a0.y * ACT_SCALE, a0.z * ACT_SCALE, a0.w * ACT_SCALE);
    v.y = pack4_fp8(a1.x * ACT_SCALE, a1.y * ACT_SCALE, a1.z * ACT_SCALE, a1.w * ACT_SCALE);
    v.z = pack4_fp8(a2.x * ACT_SCALE, a2.y * ACT_SCALE, a2.z * ACT_SCALE, a2.w * ACT_SCALE);
    v.w = pack4_fp8(a3.x * ACT_SCALE, a3.y * ACT_SCALE, a3.z * ACT_SCALE, a3.w * ACT_SCALE);
    *(uint4*)(beAb + tok * SH + ((li * 16) ^ ((tok & 1) << 4))) = v;
  }
  {
    // embed-sum + LayerNorm -> Xs fp8 x16 (8 thr/row x 32 dims)
    const int r = tid >> 3, part = tid & 7, d0 = part * 32;
    const int* vp = va + ((size_t)bt0 * Ac + r) * 3;
    int i0 = min(max(vp[0], 0), Vc - 1);
    int i1 = min(max(vp[1], 0), Vc - 1);
    int i2 = min(max(vp[2], 0), Vc - 1);
    const float4* e0 = (const float4*)(emb0 + i0 * Dc + d0);
    const float4* e1 = (const float4*)(emb1 + i1 * Dc + d0);
    const float4* e2 = (const float4*)(emb2 + i2 * Dc + d0);
    float xv[32];
    float sum = 0.f, ss = 0.f;
#pragma unroll
    for (int j = 0; j < 8; ++j) {
      float4 v0 = e0[j], v1 = e1[j], v2 = e2[j];
      float4 v;
      v.x = v0.x + v1.x + v2.x; v.y = v0.y + v1.y + v2.y;
      v.z = v0.z + v1.z + v2.z; v.w = v0.w + v1.w + v2.w;
      xv[j * 4 + 0] = v.x; xv[j * 4 + 1] = v.y; xv[j * 4 + 2] = v.z; xv[j * 4 + 3] = v.w;
      sum += v.x + v.y + v.z + v.w;
      ss += v.x * v.x + v.y * v.y + v.z * v.z + v.w * v.w;
    }
    sum += __shfl_xor(sum, 1); sum += __shfl_xor(sum, 2); sum += __shfl_xor(sum, 4);
    ss += __shfl_xor(ss, 1);   ss += __shfl_xor(ss, 2);   ss += __shfl_xor(ss, 4);
    const float mu = sum / (float)Dc;
    const float rstd = rsqrtf(ss / (float)Dc - mu * mu + 1e-5f);
    uint dw[8];
#pragma unroll
    for (int j = 0; j < 8; ++j) {
      float4 gg = *(const float4*)(ln_g + d0 + 4 * j);
      float4 bb = *(const float4*)(ln_b + d0 + 4 * j);
      float y0 = ((xv[4 * j + 0] - mu) * rstd * gg.x + bb.x) * ACT_SCALE;
      float y1 = ((xv[4 * j + 1] - mu) * rstd * gg.y + bb.y) * ACT_SCALE;
      float y2 = ((xv[4 * j + 2] - mu) * rstd * gg.z + bb.z) * ACT_SCALE;
      float y3 = ((xv[4 * j + 3] - mu) * rstd * gg.w + bb.w) * ACT_SCALE;
      dw[j] = pack4_fp8(y0, y1, y2, y3);
    }
    uint4 lo, hi;
    lo.x = dw[0]; lo.y = dw[1]; lo.z = dw[2]; lo.w = dw[3];
    hi.x = dw[4]; hi.y = dw[5]; hi.z = dw[6]; hi.w = dw[7];
    const int swr = (r & 1) << 4;
    *(uint4*)(Xs + r * SX + (d0 ^ swr)) = lo;
    *(uint4*)(Xs + r * SX + ((d0 + 16) ^ swr)) = hi;
  }
  __syncthreads();

  // ---- layer1: X(64x256) @ kW1 -> H1(64x512) relu. 8 waves x 4wt x 4at ----
  layer128<2, 4, 4, true, 0, SX, SH, 15>(Xs, H1, kW1f + (size_t)p * 32768,
                                         kb1 + p * Hc, wu * 4, lane);
  __syncthreads();

  // ---- layer2: H1(64x512) @ kW2 -> H2(64x512) relu ----
  layer128<4, 4, 4, true, 0, SH, SH, 15>(H1, H2, kW2f + (size_t)p * 65536,
                                         kb2 + p * Hc, wu * 4, lane);
  __syncthreads();

  // ---- layer3 (all 8 waves) -> KV bf16; then query -> QY fp32 ----
  layer128<4, 1, 4, false, 1, SH, SKV, 15>(H2, (void*)KV, kW3f + (size_t)p * 16384,
                                           kb3 + p * Qc, wu, lane);
  layer128<4, 1, 1, false, 2, SH, SQY, 3>(beAb, (void*)QYs, qWf + (size_t)p * 16384,
                                          qb + p * Qc, wu, lane);
  __syncthreads();

  // ---- attn[r] = <QY[tok], KV[r]> / sqrt(Q) (8 thr/row x 16 dims) ----
  {
    const int r = tid >> 3, part = tid & 7, tok = r >> 4;
    const uint2v* kpu = (const uint2v*)(KV + r * SKV + part * 16);
    const float4* qp4 = (const float4*)(QYs + tok * SQY + part * 16);
    float s = 0.f;
#pragma unroll
    for (int j = 0; j < 4; ++j) {
      uint2v kk = kpu[j];
      float4 qq = qp4[j];
      s += bf2f((short)(kk.x & 0xffff)) * qq.x;
      s += bf2f((short)(kk.x >> 16)) * qq.y;
      s += bf2f((short)(kk.y & 0xffff)) * qq.z;
      s += bf2f((short)(kk.y >> 16)) * qq.w;
    }
    s += __shfl_xor(s, 1); s += __shfl_xor(s, 2); s += __shfl_xor(s, 4);
    if (part == 0) attn_s[r] = s * 0.08838834764831845f;  // 1/sqrt(128)
  }
  __syncthreads();

  // ---- mask, signal weight, log_softmax, store (one thread per token) ----
  if (tid < 4) {
    const int tok = tid;
    const int bt = bt0 + tok;
    float av[Ac];
    int nv = 0;
#pragma unroll
    for (int a = 0; a < Ac; ++a) {
      int iv = inval_s[tok * Ac + a];
      nv += iv ? 0 : 1;
      av[a] = iv ? NEG_BIG : attn_s[tok * Ac + a];
    }
    if (ph_s[tok] == 1) {
      const int nt = NTk - tr_s[tok];
      float dp = 1.f;
      for (int i = 0; i < nt; ++i) dp *= 0.6f;
      const float ps = 0.4f / (1.f - dp);
      float wgt = (nv == 1) ? 0.f : logf(fmaxf((1.f - ps) / ps * ((float)nv - 1.f), 1e-5f));
      av[0] += wgt;
    }
    float m = NEG_BIG;
#pragma unroll
    for (int a = 0; a < Ac; ++a) m = fmaxf(m, av[a]);
    float s = 0.f;
#pragma unroll
    for (int a = 0; a < Ac; ++a) s += expf(av[a] - m);
    const float lse = logf(s) + m;
#pragma unroll
    for (int a = 0; a < Ac; ++a)
      out[bt * Ac + a] = inval_s[tok * Ac + a] ? NEG_BIG : (av[a] - lse);
  }
}

extern "C" void kernel_launch(void* const* d_in, const int* in_sizes, int n_in,
                              void* d_out, int out_size, void* d_ws, size_t ws_size,
                              hipStream_t stream) {
  const float* be   = (const float*)d_in[0];
  const int*   va   = (const int*)d_in[1];
  const int*   ph   = (const int*)d_in[2];
  const int*   tr   = (const int*)d_in[3];
  const float* emb0 = (const float*)d_in[4];
  const float* emb1 = (const float*)d_in[5];
  const float* emb2 = (const float*)d_in[6];
  const float* lng  = (const float*)d_in[7];
  const float* lnb  = (const float*)d_in[8];
  const float* kW1  = (const float*)d_in[9];
  const float* kb1  = (const float*)d_in[10];
  const float* kW2  = (const float*)d_in[11];
  const float* kb2  = (const float*)d_in[12];
  const float* kW3  = (const float*)d_in[13];
  const float* kb3  = (const float*)d_in[14];
  const float* qW   = (const float*)d_in[15];
  const float* qb   = (const float*)d_in[16];
  float* out = (float*)d_out;

  // d_ws (fp8 K=128 fragments): kW1f 512KB | kW2f 1MB | kW3f 256KB | qWf 256KB = 2MB
  int* kW1f = (int*)d_ws;
  int* kW2f = kW1f + 131072;
  int* kW3f = kW2f + 262144;
  int* qWf  = kW3f + 65536;

  transform_all<<<256, 256, 0, stream>>>(kW1, kW2, kW3, qW, kW1f, kW2f, kW3f, qWf);

  policy_main<<<4096, 512, 0, stream>>>(be, va, ph, tr, emb0, emb1, emb2, lng, lnb,
                                        kb1, kb2, kb3, qb, kW1f, kW2f, kW3f, qWf, out);
}

// Round 2
// 348.226 us; speedup vs baseline: 1.0645x; 1.0645x over previous
//
#include <hip/hip_runtime.h>
#include <hip/hip_bf16.h>
#include <cmath>

// Problem constants
constexpr int Bc = 128, Tc = 128, Ac = 16;
constexpr int Dc = 256, Hc = 512, Qc = 128, QIc = 512, Vc = 64, NTk = 13;
// Masked logits: ref emits -inf; harness needs finite there.
constexpr float NEG_BIG = -1e30f;
// fp8 scaling: weights x16, activations x16 (exact pow2), acc x 1/256.
constexpr float ACT_SCALE = 16.f;
constexpr float ACC_SCALE = 1.f / 256.f;
constexpr float ACC_TO_ACT = 1.f / 16.f;  // ACC_SCALE*ACT_SCALE (epilogue fold)

typedef unsigned int uint;
typedef uint uint2v __attribute__((ext_vector_type(2)));
typedef int i32x8 __attribute__((ext_vector_type(8)));
typedef float f32x4 __attribute__((ext_vector_type(4)));

// MX-scaled fp8 MFMA, K=128, unit E8M0 scales (0x7F = 2^0). cbsz=0/blgp=0 = fp8 e4m3.
#define MFMA128(a, b, c) __builtin_amdgcn_mfma_scale_f32_16x16x128_f8f6f4( \
    (a), (b), (c), 0, 0, 0, 0x7F7F7F7F, 0, 0x7F7F7F7F)

__device__ __forceinline__ unsigned short f2bfu(float f) {
  __hip_bfloat16 h = __float2bfloat16(f);
  return *(unsigned short*)&h;
}
__device__ __forceinline__ float bf2f(short s) {
  return __uint_as_float(((unsigned)(unsigned short)s) << 16);
}
__device__ __forceinline__ uint pack4_fp8(float a, float b, float c, float d) {
  uint v = 0;
  v = __builtin_amdgcn_cvt_pk_fp8_f32(a, b, v, 0);
  v = __builtin_amdgcn_cvt_pk_fp8_f32(c, d, v, 1);
  return v;
}

// ---------------------------------------------------------------------------
// Weight transform: fp32 [P][K][N] -> fp8 (x16) K=128 MFMA A-fragments.
// frag[p][nt][kc][lane][32B]: n = nt*16 + (lane&15),
//   k = kc*128 + (lane>>4)*32 + byte (32 contiguous k-bytes per lane).
// A/B lane->k maps are symmetric on gfx950 16x16; B side (LDS activations)
// uses the identical byte<->k convention, so any shared bijection is
// self-consistent, and unit scales make scale-block mapping irrelevant.
// (Layout verified: r1 passed with this transform.)
// ---------------------------------------------------------------------------
__global__ void transform_all(const float* __restrict__ kW1, const float* __restrict__ kW2,
                              const float* __restrict__ kW3, const float* __restrict__ qW,
                              int* __restrict__ kW1f, int* __restrict__ kW2f,
                              int* __restrict__ kW3f, int* __restrict__ qWf) {
  int gid = blockIdx.x * 256 + threadIdx.x;  // 65536 total
  const float* W;
  int* dst;
  int NT, KC, N, local;
  if (gid < 16384) {            // kW1: P4 x NT32 x KC2
    W = kW1; dst = kW1f; NT = 32; KC = 2; N = 512; local = gid;
  } else if (gid < 49152) {     // kW2: P4 x NT32 x KC4
    W = kW2; dst = kW2f; NT = 32; KC = 4; N = 512; local = gid - 16384;
  } else if (gid < 57344) {     // kW3: P4 x NT8 x KC4
    W = kW3; dst = kW3f; NT = 8; KC = 4; N = 128; local = gid - 49152;
  } else {                      // qW:  P4 x NT8 x KC4
    W = qW; dst = qWf; NT = 8; KC = 4; N = 128; local = gid - 57344;
  }
  int lane = local & 63;
  int frag = local >> 6;
  int kc = frag % KC;
  int rest = frag / KC;
  int nt = rest % NT;
  int pp = rest / NT;
  int K = KC * 128;
  int n = nt * 16 + (lane & 15);
  int k0 = kc * 128 + (lane >> 4) * 32;
  const float* src = W + ((size_t)pp * K + k0) * N + n;
  i32x8 v;
#pragma unroll
  for (int jj = 0; jj < 8; ++jj) {
    float f0 = src[(size_t)(4 * jj + 0) * N] * ACT_SCALE;
    float f1 = src[(size_t)(4 * jj + 1) * N] * ACT_SCALE;
    float f2 = src[(size_t)(4 * jj + 2) * N] * ACT_SCALE;
    float f3 = src[(size_t)(4 * jj + 3) * N] * ACT_SCALE;
    v[jj] = (int)pack4_fp8(f0, f1, f2, f3);
  }
  *(i32x8*)(dst + (size_t)local * 8) = v;
}

// ---------------------------------------------------------------------------
// K=128 MX fp8 MFMA layer, operand-swapped (weights = A, activations = B).
// One wave: WT weight(outdim)-tiles x AT action-tiles, K = KC*128.
// WT=2 keeps live regs = acc 32 + bfr 32 + wv 8 + misc ~90 < 128 cap
// (r1's WT=4 needed ~115 -> spilled: WRITE_SIZE 3.4->79.5MB, dur +10%).
// L1/L2 are invoked twice with wt0 split over the n-range instead.
// B-frag: lane (c=lane&15, q=lane>>4) reads 32B at row c(+16*at), logical
// byte off q*32 + kc*128, with 1-bit bank half-swap: physical ^= (c&1)<<4.
// C/D: lane holds action col = lane&15, 4 consecutive outdims (4q+r).
// Weight A-frag: scalar (readfirstlane'd) base + lane*32B -> saddr loads.
// OUTMODE: 0 = fp8 x16 (hidden, swizzled write), 1 = bf16 KV (linear),
//          2 = fp32 token rows (QY, linear).  CMASK: row clamp for beA(4 rows).
// ---------------------------------------------------------------------------
template <int KC, int WT, int AT, bool RELU, int OUTMODE, int SIN, int SOUT, int CMASK>
__device__ __forceinline__ void layer128(
    const char* __restrict__ aB, void* __restrict__ o0,
    const int* __restrict__ Wfi, const float* __restrict__ bias,
    int wt0, int lane) {
  const int c = lane & 15, q = lane >> 4;
  const int sw = (c & 1) << 4;
  const char* ap = aB + (c & CMASK) * SIN + q * 32;

  f32x4 acc[WT][AT];
#pragma unroll
  for (int wt = 0; wt < WT; ++wt)
#pragma unroll
    for (int at = 0; at < AT; ++at)
#pragma unroll
      for (int r = 0; r < 4; ++r) acc[wt][at][r] = 0.f;

#pragma unroll 1
  for (int kc = 0; kc < KC; ++kc) {
    i32x8 bfr[AT];
#pragma unroll
    for (int at = 0; at < AT; ++at) {
      const char* pa = ap + at * 16 * SIN + kc * 128;
      uint4 u0 = *(const uint4*)(pa + sw);
      uint4 u1 = *(const uint4*)(pa + (16 ^ sw));
      i32x8 bv;
      bv[0] = (int)u0.x; bv[1] = (int)u0.y; bv[2] = (int)u0.z; bv[3] = (int)u0.w;
      bv[4] = (int)u1.x; bv[5] = (int)u1.y; bv[6] = (int)u1.z; bv[7] = (int)u1.w;
      bfr[at] = bv;
    }
#pragma unroll
    for (int wt = 0; wt < WT; ++wt) {
      // wt0 is SGPR (readfirstlane) -> scalar base + lane*32B voffset
      const i32x8 wv = *(const i32x8*)(Wfi + ((size_t)((wt0 + wt) * KC + kc)) * 512 + lane * 8);
#pragma unroll
      for (int at = 0; at < AT; ++at)
        acc[wt][at] = MFMA128(wv, bfr[at], acc[wt][at]);
    }
  }

#pragma unroll
  for (int wt = 0; wt < WT; ++wt) {
    const int nb = (wt0 + wt) * 16 + 4 * q;  // outdim base for this lane
    float4 bv = *(const float4*)(bias + nb);
#pragma unroll
    for (int at = 0; at < AT; ++at) {
      const int row = at * 16 + c;  // action row
      if (OUTMODE == 0) {
        float s0 = fmaf(acc[wt][at][0], ACC_TO_ACT, bv.x * ACT_SCALE);
        float s1 = fmaf(acc[wt][at][1], ACC_TO_ACT, bv.y * ACT_SCALE);
        float s2 = fmaf(acc[wt][at][2], ACC_TO_ACT, bv.z * ACT_SCALE);
        float s3 = fmaf(acc[wt][at][3], ACC_TO_ACT, bv.w * ACT_SCALE);
        if (RELU) {
          s0 = fmaxf(s0, 0.f); s1 = fmaxf(s1, 0.f);
          s2 = fmaxf(s2, 0.f); s3 = fmaxf(s3, 0.f);
        }
        // swizzled write: bit4 of byte-offset ^= row parity (matches reader)
        *(uint*)((char*)o0 + row * SOUT + (nb ^ sw)) = pack4_fp8(s0, s1, s2, s3);
      } else if (OUTMODE == 1) {
        float s0 = fmaf(acc[wt][at][0], ACC_SCALE, bv.x);
        float s1 = fmaf(acc[wt][at][1], ACC_SCALE, bv.y);
        float s2 = fmaf(acc[wt][at][2], ACC_SCALE, bv.z);
        float s3 = fmaf(acc[wt][at][3], ACC_SCALE, bv.w);
        uint2v u;
        u.x = ((uint)f2bfu(s1) << 16) | f2bfu(s0);
        u.y = ((uint)f2bfu(s3) << 16) | f2bfu(s2);
        *(uint2v*)((short*)o0 + row * SOUT + nb) = u;
      } else {
        if (c < 4) {  // only real token rows
          float4 st;
          st.x = fmaf(acc[wt][at][0], ACC_SCALE, bv.x);
          st.y = fmaf(acc[wt][at][1], ACC_SCALE, bv.y);
          st.z = fmaf(acc[wt][at][2], ACC_SCALE, bv.z);
          st.w = fmaf(acc[wt][at][3], ACC_SCALE, bv.w);
          *(float4*)((float*)o0 + c * SOUT + nb) = st;
        }
      }
    }
  }
}

// ---------------------------------------------------------------------------
// Main fused kernel: 512 threads (8 waves), 64 rows (4 tokens x 16 actions).
// L1/L2 run as two WT=2 half-calls over the n-range (register-pressure fix);
// B panel re-read from LDS, weights still read exactly once.
// launch_bounds(512,4): cap 128 unified; ~90 live -> no spill, 2 blocks/CU.
// phase = blockIdx&3 -> per-phase 512KB fp8 weight set stays L2-resident.
// ---------------------------------------------------------------------------
constexpr int SX = 288;   // Xs row stride bytes  (256 data + 32; ==32 mod 128)
constexpr int SH = 544;   // H1/H2/beA row stride (512 data + 32; ==32 mod 128)
constexpr int SKV = 136;  // KV stride (bf16 elems, linear)
constexpr int SQY = 132;  // QY stride (fp32 elems, linear)

__global__ __launch_bounds__(512, 4) void policy_main(
    const float* __restrict__ be, const int* __restrict__ va,
    const int* __restrict__ phase, const int* __restrict__ trick,
    const float* __restrict__ emb0, const float* __restrict__ emb1,
    const float* __restrict__ emb2, const float* __restrict__ ln_g,
    const float* __restrict__ ln_b,
    const float* __restrict__ kb1, const float* __restrict__ kb2,
    const float* __restrict__ kb3, const float* __restrict__ qb,
    const int* __restrict__ kW1f, const int* __restrict__ kW2f,
    const int* __restrict__ kW3f, const int* __restrict__ qWf,
    float* __restrict__ out) {
  __shared__ __align__(16) char bufA[64 * SH];   // Xs [64][SX] then H2 [64][SH]
  __shared__ __align__(16) char bufB[64 * SH];   // H1 [64][SH]; then KV [64][SKV] bf16
  __shared__ __align__(16) char beAb[4 * SH];    // be tokens fp8 (4 rows, swizzled)
  __shared__ __align__(16) float QYs[4 * SQY];
  __shared__ float attn_s[64];
  __shared__ int inval_s[64];
  __shared__ int ph_s[4], tr_s[4];

  char* Xs = bufA;
  char* H2 = bufA;
  char* H1 = bufB;
  short* KV = (short*)bufB;  // H1 dead after layer2

  const int tid = threadIdx.x;
  const int lane = tid & 63;
  const int wu = __builtin_amdgcn_readfirstlane(tid >> 6);  // wave id -> SGPR
  const int p = blockIdx.x & 3;
  const int g = blockIdx.x >> 2;
  const int b = g >> 3;
  const int t0 = p * 32 + (g & 7) * 4;
  const int bt0 = b * Tc + t0;

  // ---- stage 0 (no internal barrier): masks, phase/trick, beA, LN->Xs ----
  if (tid < 64) {
    inval_s[tid] = (va[((size_t)bt0 * Ac + tid) * 3] == -1);
  } else if (tid < 68) {
    ph_s[tid - 64] = phase[bt0 + tid - 64];
  } else if (tid < 72) {
    tr_s[tid - 68] = trick[bt0 + tid - 68];
  }
  if (tid < 128) {  // beA: 4 token rows x 512 dims fp8 (x16), swizzled 16B units
    const int tok = tid >> 5, li = tid & 31;
    const float4* bp4 = (const float4*)(be + ((size_t)(bt0 + tok)) * QIc + li * 16);
    float4 a0 = bp4[0], a1 = bp4[1], a2 = bp4[2], a3 = bp4[3];
    uint4 v;
    v.x = pack4_fp8(a0.x * ACT_SCALE, a0.y * ACT_SCALE, a0.z * ACT_SCALE, a0.w * ACT_SCALE);
    v.y = pack4_fp8(a1.x * ACT_SCALE, a1.y * ACT_SCALE, a1.z * ACT_SCALE, a1.w * ACT_SCALE);
    v.z = pack4_fp8(a2.x * ACT_SCALE, a2.y * ACT_SCALE, a2.z * ACT_SCALE, a2.w * ACT_SCALE);
    v.w = pack4_fp8(a3.x * ACT_SCALE, a3.y * ACT_SCALE, a3.z * ACT_SCALE, a3.w * ACT_SCALE);
    *(uint4*)(beAb + tok * SH + ((li * 16) ^ ((tok & 1) << 4))) = v;
  }
  {
    // embed-sum + LayerNorm -> Xs fp8 x16 (8 thr/row x 32 dims)
    const int r = tid >> 3, part = tid & 7, d0 = part * 32;
    const int* vp = va + ((size_t)bt0 * Ac + r) * 3;
    int i0 = min(max(vp[0], 0), Vc - 1);
    int i1 = min(max(vp[1], 0), Vc - 1);
    int i2 = min(max(vp[2], 0), Vc - 1);
    const float4* e0 = (const float4*)(emb0 + i0 * Dc + d0);
    const float4* e1 = (const float4*)(emb1 + i1 * Dc + d0);
    const float4* e2 = (const float4*)(emb2 + i2 * Dc + d0);
    float xv[32];
    float sum = 0.f, ss = 0.f;
#pragma unroll
    for (int j = 0; j < 8; ++j) {
      float4 v0 = e0[j], v1 = e1[j], v2 = e2[j];
      float4 v;
      v.x = v0.x + v1.x + v2.x; v.y = v0.y + v1.y + v2.y;
      v.z = v0.z + v1.z + v2.z; v.w = v0.w + v1.w + v2.w;
      xv[j * 4 + 0] = v.x; xv[j * 4 + 1] = v.y; xv[j * 4 + 2] = v.z; xv[j * 4 + 3] = v.w;
      sum += v.x + v.y + v.z + v.w;
      ss += v.x * v.x + v.y * v.y + v.z * v.z + v.w * v.w;
    }
    sum += __shfl_xor(sum, 1); sum += __shfl_xor(sum, 2); sum += __shfl_xor(sum, 4);
    ss += __shfl_xor(ss, 1);   ss += __shfl_xor(ss, 2);   ss += __shfl_xor(ss, 4);
    const float mu = sum / (float)Dc;
    const float rstd = rsqrtf(ss / (float)Dc - mu * mu + 1e-5f);
    uint dw[8];
#pragma unroll
    for (int j = 0; j < 8; ++j) {
      float4 gg = *(const float4*)(ln_g + d0 + 4 * j);
      float4 bb = *(const float4*)(ln_b + d0 + 4 * j);
      float y0 = ((xv[4 * j + 0] - mu) * rstd * gg.x + bb.x) * ACT_SCALE;
      float y1 = ((xv[4 * j + 1] - mu) * rstd * gg.y + bb.y) * ACT_SCALE;
      float y2 = ((xv[4 * j + 2] - mu) * rstd * gg.z + bb.z) * ACT_SCALE;
      float y3 = ((xv[4 * j + 3] - mu) * rstd * gg.w + bb.w) * ACT_SCALE;
      dw[j] = pack4_fp8(y0, y1, y2, y3);
    }
    uint4 lo, hi;
    lo.x = dw[0]; lo.y = dw[1]; lo.z = dw[2]; lo.w = dw[3];
    hi.x = dw[4]; hi.y = dw[5]; hi.z = dw[6]; hi.w = dw[7];
    const int swr = (r & 1) << 4;
    *(uint4*)(Xs + r * SX + (d0 ^ swr)) = lo;
    *(uint4*)(Xs + r * SX + ((d0 + 16) ^ swr)) = hi;
  }
  __syncthreads();

  // ---- layer1: X(64x256) @ kW1 -> H1(64x512) relu. 2 half-calls x WT=2 ----
  layer128<2, 2, 4, true, 0, SX, SH, 15>(Xs, H1, kW1f + (size_t)p * 32768,
                                         kb1 + p * Hc, wu * 2, lane);
  __builtin_amdgcn_sched_barrier(0);
  layer128<2, 2, 4, true, 0, SX, SH, 15>(Xs, H1, kW1f + (size_t)p * 32768,
                                         kb1 + p * Hc, 16 + wu * 2, lane);
  __syncthreads();

  // ---- layer2: H1(64x512) @ kW2 -> H2(64x512) relu. 2 half-calls x WT=2 ----
  layer128<4, 2, 4, true, 0, SH, SH, 15>(H1, H2, kW2f + (size_t)p * 65536,
                                         kb2 + p * Hc, wu * 2, lane);
  __builtin_amdgcn_sched_barrier(0);
  layer128<4, 2, 4, true, 0, SH, SH, 15>(H1, H2, kW2f + (size_t)p * 65536,
                                         kb2 + p * Hc, 16 + wu * 2, lane);
  __syncthreads();

  // ---- layer3 (all 8 waves) -> KV bf16; then query -> QY fp32 ----
  layer128<4, 1, 4, false, 1, SH, SKV, 15>(H2, (void*)KV, kW3f + (size_t)p * 16384,
                                           kb3 + p * Qc, wu, lane);
  __builtin_amdgcn_sched_barrier(0);
  layer128<4, 1, 1, false, 2, SH, SQY, 3>(beAb, (void*)QYs, qWf + (size_t)p * 16384,
                                          qb + p * Qc, wu, lane);
  __syncthreads();

  // ---- attn[r] = <QY[tok], KV[r]> / sqrt(Q) (8 thr/row x 16 dims) ----
  {
    const int r = tid >> 3, part = tid & 7, tok = r >> 4;
    const uint2v* kpu = (const uint2v*)(KV + r * SKV + part * 16);
    const float4* qp4 = (const float4*)(QYs + tok * SQY + part * 16);
    float s = 0.f;
#pragma unroll
    for (int j = 0; j < 4; ++j) {
      uint2v kk = kpu[j];
      float4 qq = qp4[j];
      s += bf2f((short)(kk.x & 0xffff)) * qq.x;
      s += bf2f((short)(kk.x >> 16)) * qq.y;
      s += bf2f((short)(kk.y & 0xffff)) * qq.z;
      s += bf2f((short)(kk.y >> 16)) * qq.w;
    }
    s += __shfl_xor(s, 1); s += __shfl_xor(s, 2); s += __shfl_xor(s, 4);
    if (part == 0) attn_s[r] = s * 0.08838834764831845f;  // 1/sqrt(128)
  }
  __syncthreads();

  // ---- mask, signal weight, log_softmax, store (one thread per token) ----
  if (tid < 4) {
    const int tok = tid;
    const int bt = bt0 + tok;
    float av[Ac];
    int nv = 0;
#pragma unroll
    for (int a = 0; a < Ac; ++a) {
      int iv = inval_s[tok * Ac + a];
      nv += iv ? 0 : 1;
      av[a] = iv ? NEG_BIG : attn_s[tok * Ac + a];
    }
    if (ph_s[tok] == 1) {
      const int nt = NTk - tr_s[tok];
      float dp = 1.f;
      for (int i = 0; i < nt; ++i) dp *= 0.6f;
      const float ps = 0.4f / (1.f - dp);
      float wgt = (nv == 1) ? 0.f : logf(fmaxf((1.f - ps) / ps * ((float)nv - 1.f), 1e-5f));
      av[0] += wgt;
    }
    float m = NEG_BIG;
#pragma unroll
    for (int a = 0; a < Ac; ++a) m = fmaxf(m, av[a]);
    float s = 0.f;
#pragma unroll
    for (int a = 0; a < Ac; ++a) s += expf(av[a] - m);
    const float lse = logf(s) + m;
#pragma unroll
    for (int a = 0; a < Ac; ++a)
      out[bt * Ac + a] = inval_s[tok * Ac + a] ? NEG_BIG : (av[a] - lse);
  }
}

extern "C" void kernel_launch(void* const* d_in, const int* in_sizes, int n_in,
                              void* d_out, int out_size, void* d_ws, size_t ws_size,
                              hipStream_t stream) {
  const float* be   = (const float*)d_in[0];
  const int*   va   = (const int*)d_in[1];
  const int*   ph   = (const int*)d_in[2];
  const int*   tr   = (const int*)d_in[3];
  const float* emb0 = (const float*)d_in[4];
  const float* emb1 = (const float*)d_in[5];
  const float* emb2 = (const float*)d_in[6];
  const float* lng  = (const float*)d_in[7];
  const float* lnb  = (const float*)d_in[8];
  const float* kW1  = (const float*)d_in[9];
  const float* kb1  = (const float*)d_in[10];
  const float* kW2  = (const float*)d_in[11];
  const float* kb2  = (const float*)d_in[12];
  const float* kW3  = (const float*)d_in[13];
  const float* kb3  = (const float*)d_in[14];
  const float* qW   = (const float*)d_in[15];
  const float* qb   = (const float*)d_in[16];
  float* out = (float*)d_out;

  // d_ws (fp8 K=128 fragments): kW1f 512KB | kW2f 1MB | kW3f 256KB | qWf 256KB = 2MB
  int* kW1f = (int*)d_ws;
  int* kW2f = kW1f + 131072;
  int* kW3f = kW2f + 262144;
  int* qWf  = kW3f + 65536;

  transform_all<<<256, 256, 0, stream>>>(kW1, kW2, kW3, qW, kW1f, kW2f, kW3f, qWf);

  policy_main<<<4096, 512, 0, stream>>>(be, va, ph, tr, emb0, emb1, emb2, lng, lnb,
                                        kb1, kb2, kb3, qb, kW1f, kW2f, kW3f, qWf, out);
}

// Round 3
// 345.533 us; speedup vs baseline: 1.0728x; 1.0078x over previous
//
#include <hip/hip_runtime.h>
#include <hip/hip_bf16.h>
#include <cmath>

// Problem constants
constexpr int Bc = 128, Tc = 128, Ac = 16;
constexpr int Dc = 256, Hc = 512, Qc = 128, QIc = 512, Vc = 64, NTk = 13;
// Masked logits: ref emits -inf; harness needs finite there.
constexpr float NEG_BIG = -1e30f;
// fp8 scaling: weights x16, activations x16 (exact pow2), acc x 1/256.
constexpr float ACT_SCALE = 16.f;
constexpr float ACC_SCALE = 1.f / 256.f;
constexpr float ACC_TO_ACT = 1.f / 16.f;  // ACC_SCALE*ACT_SCALE (epilogue fold)

typedef unsigned int uint;
typedef uint uint2v __attribute__((ext_vector_type(2)));
typedef int i32x8 __attribute__((ext_vector_type(8)));
typedef float f32x4 __attribute__((ext_vector_type(4)));

// MX-scaled fp8 MFMA, K=128, unit E8M0 scales (0x7F = 2^0). cbsz=0/blgp=0 = fp8 e4m3.
#define MFMA128(a, b, c) __builtin_amdgcn_mfma_scale_f32_16x16x128_f8f6f4( \
    (a), (b), (c), 0, 0, 0, 0x7F7F7F7F, 0, 0x7F7F7F7F)

__device__ __forceinline__ unsigned short f2bfu(float f) {
  __hip_bfloat16 h = __float2bfloat16(f);
  return *(unsigned short*)&h;
}
__device__ __forceinline__ float bf2f(short s) {
  return __uint_as_float(((unsigned)(unsigned short)s) << 16);
}
__device__ __forceinline__ uint pack4_fp8(float a, float b, float c, float d) {
  uint v = 0;
  v = __builtin_amdgcn_cvt_pk_fp8_f32(a, b, v, 0);
  v = __builtin_amdgcn_cvt_pk_fp8_f32(c, d, v, 1);
  return v;
}

// ---------------------------------------------------------------------------
// Weight transform: fp32 [P][K][N] -> fp8 (x16) K=128 MFMA A-fragments.
// frag[p][nt][kc][lane][32B]: n = nt*16 + (lane&15),
//   k = kc*128 + (lane>>4)*32 + byte (32 contiguous k-bytes per lane).
// Layout verified (r1/r2 passed).
// ---------------------------------------------------------------------------
__global__ void transform_all(const float* __restrict__ kW1, const float* __restrict__ kW2,
                              const float* __restrict__ kW3, const float* __restrict__ qW,
                              int* __restrict__ kW1f, int* __restrict__ kW2f,
                              int* __restrict__ kW3f, int* __restrict__ qWf) {
  int gid = blockIdx.x * 256 + threadIdx.x;  // 65536 total
  const float* W;
  int* dst;
  int NT, KC, N, local;
  if (gid < 16384) {            // kW1: P4 x NT32 x KC2
    W = kW1; dst = kW1f; NT = 32; KC = 2; N = 512; local = gid;
  } else if (gid < 49152) {     // kW2: P4 x NT32 x KC4
    W = kW2; dst = kW2f; NT = 32; KC = 4; N = 512; local = gid - 16384;
  } else if (gid < 57344) {     // kW3: P4 x NT8 x KC4
    W = kW3; dst = kW3f; NT = 8; KC = 4; N = 128; local = gid - 49152;
  } else {                      // qW:  P4 x NT8 x KC4
    W = qW; dst = qWf; NT = 8; KC = 4; N = 128; local = gid - 57344;
  }
  int lane = local & 63;
  int frag = local >> 6;
  int kc = frag % KC;
  int rest = frag / KC;
  int nt = rest % NT;
  int pp = rest / NT;
  int K = KC * 128;
  int n = nt * 16 + (lane & 15);
  int k0 = kc * 128 + (lane >> 4) * 32;
  const float* src = W + ((size_t)pp * K + k0) * N + n;
  i32x8 v;
#pragma unroll
  for (int jj = 0; jj < 8; ++jj) {
    float f0 = src[(size_t)(4 * jj + 0) * N] * ACT_SCALE;
    float f1 = src[(size_t)(4 * jj + 1) * N] * ACT_SCALE;
    float f2 = src[(size_t)(4 * jj + 2) * N] * ACT_SCALE;
    float f3 = src[(size_t)(4 * jj + 3) * N] * ACT_SCALE;
    v[jj] = (int)pack4_fp8(f0, f1, f2, f3);
  }
  *(i32x8*)(dst + (size_t)local * 8) = v;
}

// ---------------------------------------------------------------------------
// K=128 MX fp8 MFMA layer, operand-swapped (weights = A, activations = B),
// SOFTWARE-PIPELINED (r3): latency-bound fix. All loops fully unrolled;
// B-frags use a 2-deep ring (bfA/bfB, parity of flattened (kc,at) index —
// compile-time, no dynamic reg indexing); weights preloaded entirely when
// KC*WT<=4, else ring-2 across kc (wvA/wvB). Every load issues one group
// ahead of its consuming MFMA; sched_barrier(0) per kc-group pins the
// pipeline (loads already issued before the fence, consumed after).
// Peak live regs (L2 half): acc32 + wv32 + bf16 + misc ~95 < 128 cap.
// B-frag: lane (c=lane&15, q=lane>>4) reads 32B at row c(+16*at), logical
// byte off q*32 + kc*128, bank half-swap: physical ^= (c&1)<<4.
// C/D: lane holds action col = lane&15, 4 consecutive outdims (4q+r).
// OUTMODE: 0 = fp8 x16 (hidden, swizzled write), 1 = bf16 KV (linear),
//          2 = fp32 token rows (QY, linear).  CMASK: row clamp for beA(4 rows).
// ---------------------------------------------------------------------------
template <int KC, int WT, int AT, bool RELU, int OUTMODE, int SIN, int SOUT, int CMASK>
__device__ __forceinline__ void layer128(
    const char* __restrict__ aB, void* __restrict__ o0,
    const int* __restrict__ Wfi, const float* __restrict__ bias,
    int wt0, int lane) {
  const int c = lane & 15, q = lane >> 4;
  const int sw = (c & 1) << 4;
  const char* ap = aB + (c & CMASK) * SIN + q * 32;

#define LDB(kc_, at_) ({                                        \
    const char* pa_ = ap + (at_) * 16 * SIN + (kc_) * 128;      \
    uint4 u0_ = *(const uint4*)(pa_ + sw);                      \
    uint4 u1_ = *(const uint4*)(pa_ + (16 ^ sw));               \
    i32x8 bv_;                                                  \
    bv_[0] = (int)u0_.x; bv_[1] = (int)u0_.y;                   \
    bv_[2] = (int)u0_.z; bv_[3] = (int)u0_.w;                   \
    bv_[4] = (int)u1_.x; bv_[5] = (int)u1_.y;                   \
    bv_[6] = (int)u1_.z; bv_[7] = (int)u1_.w; bv_; })
#define LDW(wt_, kc_) \
    (*(const i32x8*)(Wfi + ((size_t)((wt0 + (wt_)) * KC + (kc_))) * 512 + lane * 8))

  f32x4 acc[WT][AT];
#pragma unroll
  for (int wt = 0; wt < WT; ++wt)
#pragma unroll
    for (int at = 0; at < AT; ++at)
#pragma unroll
      for (int r = 0; r < 4; ++r) acc[wt][at][r] = 0.f;

  i32x8 bfA, bfB;
  bfA = LDB(0, 0);

  if constexpr (KC * WT <= 4) {
    // ---- preload ALL weights (<=32 regs), B-frag ring-2 ----
    i32x8 wv[KC][WT];
#pragma unroll
    for (int kc = 0; kc < KC; ++kc)
#pragma unroll
      for (int wt = 0; wt < WT; ++wt) wv[kc][wt] = LDW(wt, kc);
#pragma unroll
    for (int kc = 0; kc < KC; ++kc) {
#pragma unroll
      for (int at = 0; at < AT; ++at) {
        const int f = kc * AT + at;
        const int nf = f + 1;
        if ((f & 1) == 0) {
          if (nf < KC * AT) bfB = LDB(nf / AT, nf % AT);
#pragma unroll
          for (int wt = 0; wt < WT; ++wt)
            acc[wt][at] = MFMA128(wv[kc][wt], bfA, acc[wt][at]);
        } else {
          if (nf < KC * AT) bfA = LDB(nf / AT, nf % AT);
#pragma unroll
          for (int wt = 0; wt < WT; ++wt)
            acc[wt][at] = MFMA128(wv[kc][wt], bfB, acc[wt][at]);
        }
      }
      __builtin_amdgcn_sched_barrier(0);
    }
  } else {
    // ---- weight ring-2 across kc (prefetch kc+1 during kc), B ring-2 ----
    i32x8 wvA[WT], wvB[WT];
#pragma unroll
    for (int wt = 0; wt < WT; ++wt) wvA[wt] = LDW(wt, 0);
#pragma unroll
    for (int kc = 0; kc < KC; ++kc) {
      const bool ke = (kc & 1) == 0;
      if (kc + 1 < KC) {
#pragma unroll
        for (int wt = 0; wt < WT; ++wt) {
          if (ke) wvB[wt] = LDW(wt, kc + 1);
          else    wvA[wt] = LDW(wt, kc + 1);
        }
      }
#pragma unroll
      for (int at = 0; at < AT; ++at) {
        const int f = kc * AT + at;
        const int nf = f + 1;
        if ((f & 1) == 0) {
          if (nf < KC * AT) bfB = LDB(nf / AT, nf % AT);
#pragma unroll
          for (int wt = 0; wt < WT; ++wt)
            acc[wt][at] = MFMA128(ke ? wvA[wt] : wvB[wt], bfA, acc[wt][at]);
        } else {
          if (nf < KC * AT) bfA = LDB(nf / AT, nf % AT);
#pragma unroll
          for (int wt = 0; wt < WT; ++wt)
            acc[wt][at] = MFMA128(ke ? wvA[wt] : wvB[wt], bfB, acc[wt][at]);
        }
      }
      __builtin_amdgcn_sched_barrier(0);
    }
  }
#undef LDB
#undef LDW

#pragma unroll
  for (int wt = 0; wt < WT; ++wt) {
    const int nb = (wt0 + wt) * 16 + 4 * q;  // outdim base for this lane
    float4 bv = *(const float4*)(bias + nb);
#pragma unroll
    for (int at = 0; at < AT; ++at) {
      const int row = at * 16 + c;  // action row
      if (OUTMODE == 0) {
        float s0 = fmaf(acc[wt][at][0], ACC_TO_ACT, bv.x * ACT_SCALE);
        float s1 = fmaf(acc[wt][at][1], ACC_TO_ACT, bv.y * ACT_SCALE);
        float s2 = fmaf(acc[wt][at][2], ACC_TO_ACT, bv.z * ACT_SCALE);
        float s3 = fmaf(acc[wt][at][3], ACC_TO_ACT, bv.w * ACT_SCALE);
        if (RELU) {
          s0 = fmaxf(s0, 0.f); s1 = fmaxf(s1, 0.f);
          s2 = fmaxf(s2, 0.f); s3 = fmaxf(s3, 0.f);
        }
        // swizzled write: bit4 of byte-offset ^= row parity (matches reader)
        *(uint*)((char*)o0 + row * SOUT + (nb ^ sw)) = pack4_fp8(s0, s1, s2, s3);
      } else if (OUTMODE == 1) {
        float s0 = fmaf(acc[wt][at][0], ACC_SCALE, bv.x);
        float s1 = fmaf(acc[wt][at][1], ACC_SCALE, bv.y);
        float s2 = fmaf(acc[wt][at][2], ACC_SCALE, bv.z);
        float s3 = fmaf(acc[wt][at][3], ACC_SCALE, bv.w);
        uint2v u;
        u.x = ((uint)f2bfu(s1) << 16) | f2bfu(s0);
        u.y = ((uint)f2bfu(s3) << 16) | f2bfu(s2);
        *(uint2v*)((short*)o0 + row * SOUT + nb) = u;
      } else {
        if (c < 4) {  // only real token rows
          float4 st;
          st.x = fmaf(acc[wt][at][0], ACC_SCALE, bv.x);
          st.y = fmaf(acc[wt][at][1], ACC_SCALE, bv.y);
          st.z = fmaf(acc[wt][at][2], ACC_SCALE, bv.z);
          st.w = fmaf(acc[wt][at][3], ACC_SCALE, bv.w);
          *(float4*)((float*)o0 + c * SOUT + nb) = st;
        }
      }
    }
  }
}

// ---------------------------------------------------------------------------
// Main fused kernel: 512 threads (8 waves), 64 rows (4 tokens x 16 actions).
// L1/L2 as two WT=2 half-calls (pressure); query call sits BETWEEN the L1
// halves (depends only on stage0's beAb) to feed the stall shadow.
// No inter-call sched_barriers: call-B prologue loads overlap call-A epilogue.
// launch_bounds(512,4): cap 128; LDS 74.75KB -> 2 blocks/CU (16 waves).
// phase = blockIdx&3 -> per-phase 512KB fp8 weight set stays L2-resident
// (block i -> XCD i%8, phase i&3: each XCD serves exactly one phase).
// ---------------------------------------------------------------------------
constexpr int SX = 288;   // Xs row stride bytes  (256 data + 32; ==32 mod 128)
constexpr int SH = 544;   // H1/H2/beA row stride (512 data + 32; ==32 mod 128)
constexpr int SKV = 136;  // KV stride (bf16 elems, linear)
constexpr int SQY = 132;  // QY stride (fp32 elems, linear)

__global__ __launch_bounds__(512, 4) void policy_main(
    const float* __restrict__ be, const int* __restrict__ va,
    const int* __restrict__ phase, const int* __restrict__ trick,
    const float* __restrict__ emb0, const float* __restrict__ emb1,
    const float* __restrict__ emb2, const float* __restrict__ ln_g,
    const float* __restrict__ ln_b,
    const float* __restrict__ kb1, const float* __restrict__ kb2,
    const float* __restrict__ kb3, const float* __restrict__ qb,
    const int* __restrict__ kW1f, const int* __restrict__ kW2f,
    const int* __restrict__ kW3f, const int* __restrict__ qWf,
    float* __restrict__ out) {
  __shared__ __align__(16) char bufA[64 * SH];   // Xs [64][SX] then H2 [64][SH]
  __shared__ __align__(16) char bufB[64 * SH];   // H1 [64][SH]; then KV [64][SKV] bf16
  __shared__ __align__(16) char beAb[4 * SH];    // be tokens fp8 (4 rows, swizzled)
  __shared__ __align__(16) float QYs[4 * SQY];
  __shared__ float attn_s[64];
  __shared__ int inval_s[64];
  __shared__ int ph_s[4], tr_s[4];

  char* Xs = bufA;
  char* H2 = bufA;
  char* H1 = bufB;
  short* KV = (short*)bufB;  // H1 dead after layer2

  const int tid = threadIdx.x;
  const int lane = tid & 63;
  const int wu = __builtin_amdgcn_readfirstlane(tid >> 6);  // wave id -> SGPR
  const int p = blockIdx.x & 3;
  const int g = blockIdx.x >> 2;
  const int b = g >> 3;
  const int t0 = p * 32 + (g & 7) * 4;
  const int bt0 = b * Tc + t0;

  // ---- stage 0 (no internal barrier): masks, phase/trick, beA, LN->Xs ----
  if (tid < 64) {
    inval_s[tid] = (va[((size_t)bt0 * Ac + tid) * 3] == -1);
  } else if (tid < 68) {
    ph_s[tid - 64] = phase[bt0 + tid - 64];
  } else if (tid < 72) {
    tr_s[tid - 68] = trick[bt0 + tid - 68];
  }
  if (tid < 128) {  // beA: 4 token rows x 512 dims fp8 (x16), swizzled 16B units
    const int tok = tid >> 5, li = tid & 31;
    const float4* bp4 = (const float4*)(be + ((size_t)(bt0 + tok)) * QIc + li * 16);
    float4 a0 = bp4[0], a1 = bp4[1], a2 = bp4[2], a3 = bp4[3];
    uint4 v;
    v.x = pack4_fp8(a0.x * ACT_SCALE, a0.y * ACT_SCALE, a0.z * ACT_SCALE, a0.w * ACT_SCALE);
    v.y = pack4_fp8(a1.x * ACT_SCALE, a1.y * ACT_SCALE, a1.z * ACT_SCALE, a1.w * ACT_SCALE);
    v.z = pack4_fp8(a2.x * ACT_SCALE, a2.y * ACT_SCALE, a2.z * ACT_SCALE, a2.w * ACT_SCALE);
    v.w = pack4_fp8(a3.x * ACT_SCALE, a3.y * ACT_SCALE, a3.z * ACT_SCALE, a3.w * ACT_SCALE);
    *(uint4*)(beAb + tok * SH + ((li * 16) ^ ((tok & 1) << 4))) = v;
  }
  {
    // embed-sum + LayerNorm -> Xs fp8 x16 (8 thr/row x 32 dims)
    const int r = tid >> 3, part = tid & 7, d0 = part * 32;
    const int* vp = va + ((size_t)bt0 * Ac + r) * 3;
    int i0 = min(max(vp[0], 0), Vc - 1);
    int i1 = min(max(vp[1], 0), Vc - 1);
    int i2 = min(max(vp[2], 0), Vc - 1);
    const float4* e0 = (const float4*)(emb0 + i0 * Dc + d0);
    const float4* e1 = (const float4*)(emb1 + i1 * Dc + d0);
    const float4* e2 = (const float4*)(emb2 + i2 * Dc + d0);
    float xv[32];
    float sum = 0.f, ss = 0.f;
#pragma unroll
    for (int j = 0; j < 8; ++j) {
      float4 v0 = e0[j], v1 = e1[j], v2 = e2[j];
      float4 v;
      v.x = v0.x + v1.x + v2.x; v.y = v0.y + v1.y + v2.y;
      v.z = v0.z + v1.z + v2.z; v.w = v0.w + v1.w + v2.w;
      xv[j * 4 + 0] = v.x; xv[j * 4 + 1] = v.y; xv[j * 4 + 2] = v.z; xv[j * 4 + 3] = v.w;
      sum += v.x + v.y + v.z + v.w;
      ss += v.x * v.x + v.y * v.y + v.z * v.z + v.w * v.w;
    }
    sum += __shfl_xor(sum, 1); sum += __shfl_xor(sum, 2); sum += __shfl_xor(sum, 4);
    ss += __shfl_xor(ss, 1);   ss += __shfl_xor(ss, 2);   ss += __shfl_xor(ss, 4);
    const float mu = sum / (float)Dc;
    const float rstd = rsqrtf(ss / (float)Dc - mu * mu + 1e-5f);
    uint dw[8];
#pragma unroll
    for (int j = 0; j < 8; ++j) {
      float4 gg = *(const float4*)(ln_g + d0 + 4 * j);
      float4 bb = *(const float4*)(ln_b + d0 + 4 * j);
      float y0 = ((xv[4 * j + 0] - mu) * rstd * gg.x + bb.x) * ACT_SCALE;
      float y1 = ((xv[4 * j + 1] - mu) * rstd * gg.y + bb.y) * ACT_SCALE;
      float y2 = ((xv[4 * j + 2] - mu) * rstd * gg.z + bb.z) * ACT_SCALE;
      float y3 = ((xv[4 * j + 3] - mu) * rstd * gg.w + bb.w) * ACT_SCALE;
      dw[j] = pack4_fp8(y0, y1, y2, y3);
    }
    uint4 lo, hi;
    lo.x = dw[0]; lo.y = dw[1]; lo.z = dw[2]; lo.w = dw[3];
    hi.x = dw[4]; hi.y = dw[5]; hi.z = dw[6]; hi.w = dw[7];
    const int swr = (r & 1) << 4;
    *(uint4*)(Xs + r * SX + (d0 ^ swr)) = lo;
    *(uint4*)(Xs + r * SX + ((d0 + 16) ^ swr)) = hi;
  }
  __syncthreads();

  // ---- layer1 half A; query (independent: beAb) fills the stall shadow ----
  layer128<2, 2, 4, true, 0, SX, SH, 15>(Xs, H1, kW1f + (size_t)p * 32768,
                                         kb1 + p * Hc, wu * 2, lane);
  layer128<4, 1, 1, false, 2, SH, SQY, 3>(beAb, (void*)QYs, qWf + (size_t)p * 16384,
                                          qb + p * Qc, wu, lane);
  // ---- layer1 half B ----
  layer128<2, 2, 4, true, 0, SX, SH, 15>(Xs, H1, kW1f + (size_t)p * 32768,
                                         kb1 + p * Hc, 16 + wu * 2, lane);
  __syncthreads();

  // ---- layer2: H1(64x512) @ kW2 -> H2(64x512) relu. 2 half-calls x WT=2 ----
  layer128<4, 2, 4, true, 0, SH, SH, 15>(H1, H2, kW2f + (size_t)p * 65536,
                                         kb2 + p * Hc, wu * 2, lane);
  layer128<4, 2, 4, true, 0, SH, SH, 15>(H1, H2, kW2f + (size_t)p * 65536,
                                         kb2 + p * Hc, 16 + wu * 2, lane);
  __syncthreads();

  // ---- layer3 (all 8 waves) -> KV bf16 ----
  layer128<4, 1, 4, false, 1, SH, SKV, 15>(H2, (void*)KV, kW3f + (size_t)p * 16384,
                                           kb3 + p * Qc, wu, lane);
  __syncthreads();

  // ---- attn[r] = <QY[tok], KV[r]> / sqrt(Q) (8 thr/row x 16 dims) ----
  {
    const int r = tid >> 3, part = tid & 7, tok = r >> 4;
    const uint2v* kpu = (const uint2v*)(KV + r * SKV + part * 16);
    const float4* qp4 = (const float4*)(QYs + tok * SQY + part * 16);
    float s = 0.f;
#pragma unroll
    for (int j = 0; j < 4; ++j) {
      uint2v kk = kpu[j];
      float4 qq = qp4[j];
      s += bf2f((short)(kk.x & 0xffff)) * qq.x;
      s += bf2f((short)(kk.x >> 16)) * qq.y;
      s += bf2f((short)(kk.y & 0xffff)) * qq.z;
      s += bf2f((short)(kk.y >> 16)) * qq.w;
    }
    s += __shfl_xor(s, 1); s += __shfl_xor(s, 2); s += __shfl_xor(s, 4);
    if (part == 0) attn_s[r] = s * 0.08838834764831845f;  // 1/sqrt(128)
  }
  __syncthreads();

  // ---- mask, signal weight, log_softmax, store (one thread per token) ----
  if (tid < 4) {
    const int tok = tid;
    const int bt = bt0 + tok;
    float av[Ac];
    int nv = 0;
#pragma unroll
    for (int a = 0; a < Ac; ++a) {
      int iv = inval_s[tok * Ac + a];
      nv += iv ? 0 : 1;
      av[a] = iv ? NEG_BIG : attn_s[tok * Ac + a];
    }
    if (ph_s[tok] == 1) {
      const int nt = NTk - tr_s[tok];
      float dp = 1.f;
      for (int i = 0; i < nt; ++i) dp *= 0.6f;
      const float ps = 0.4f / (1.f - dp);
      float wgt = (nv == 1) ? 0.f : logf(fmaxf((1.f - ps) / ps * ((float)nv - 1.f), 1e-5f));
      av[0] += wgt;
    }
    float m = NEG_BIG;
#pragma unroll
    for (int a = 0; a < Ac; ++a) m = fmaxf(m, av[a]);
    float s = 0.f;
#pragma unroll
    for (int a = 0; a < Ac; ++a) s += expf(av[a] - m);
    const float lse = logf(s) + m;
#pragma unroll
    for (int a = 0; a < Ac; ++a)
      out[bt * Ac + a] = inval_s[tok * Ac + a] ? NEG_BIG : (av[a] - lse);
  }
}

extern "C" void kernel_launch(void* const* d_in, const int* in_sizes, int n_in,
                              void* d_out, int out_size, void* d_ws, size_t ws_size,
                              hipStream_t stream) {
  const float* be   = (const float*)d_in[0];
  const int*   va   = (const int*)d_in[1];
  const int*   ph   = (const int*)d_in[2];
  const int*   tr   = (const int*)d_in[3];
  const float* emb0 = (const float*)d_in[4];
  const float* emb1 = (const float*)d_in[5];
  const float* emb2 = (const float*)d_in[6];
  const float* lng  = (const float*)d_in[7];
  const float* lnb  = (const float*)d_in[8];
  const float* kW1  = (const float*)d_in[9];
  const float* kb1  = (const float*)d_in[10];
  const float* kW2  = (const float*)d_in[11];
  const float* kb2  = (const float*)d_in[12];
  const float* kW3  = (const float*)d_in[13];
  const float* kb3  = (const float*)d_in[14];
  const float* qW   = (const float*)d_in[15];
  const float* qb   = (const float*)d_in[16];
  float* out = (float*)d_out;

  // d_ws (fp8 K=128 fragments): kW1f 512KB | kW2f 1MB | kW3f 256KB | qWf 256KB = 2MB
  int* kW1f = (int*)d_ws;
  int* kW2f = kW1f + 131072;
  int* kW3f = kW2f + 262144;
  int* qWf  = kW3f + 65536;

  transform_all<<<256, 256, 0, stream>>>(kW1, kW2, kW3, qW, kW1f, kW2f, kW3f, qWf);

  policy_main<<<4096, 512, 0, stream>>>(be, va, ph, tr, emb0, emb1, emb2, lng, lnb,
                                        kb1, kb2, kb3, qb, kW1f, kW2f, kW3f, qWf, out);
}